// Round 7
// baseline (897.874 us; speedup 1.0000x reference)
//
#include <hip/hip_runtime.h>
#include <hip/hip_fp16.h>

typedef _Float16 f16x2 __attribute__((ext_vector_type(2)));
typedef _Float16 half8 __attribute__((ext_vector_type(8)));

#define TS  512
#define HID 256
#define G3  768
#define EMB 128
#define THR 512   // threads per pipe block
#define NB1 12    // xi1 producer blocks
#define RPB 64    // rows per xi1-stage block
#define CTL 511   // poller/publisher thread
#define BSZ 8     // handshake batch (steps)

__device__ __forceinline__ float sigmoidf_(float x){ return 1.0f/(1.0f+__expf(-x)); }
__device__ __forceinline__ float tanhf_(float x){
  float e = __expf(-2.0f*fabsf(x));
  float t = (1.0f-e)/(1.0f+e);
  return copysignf(t,x);
}

// K1: xi0[t][j] = bih0[j] + sum_k Wih0[j][k] * emb[x[t,511]][k]
// + packs the L2-streamed weight rows (I=10..11 of each 12-row group) to f16.
__global__ __launch_bounds__(256) void xi0_kernel(const int* __restrict__ x,
    const float* __restrict__ emb_tab, const float* __restrict__ Wih0,
    const float* __restrict__ bih0, float* __restrict__ xi0,
    const float* __restrict__ Whh0, const float* __restrict__ Whh1,
    _Float16* __restrict__ wpk0, _Float16* __restrict__ wpk1)
{
  __shared__ float embs[8][EMB];
  __shared__ int idx8[8];
  int tid = threadIdx.x;
  int t0  = blockIdx.x * 8;
  if (tid < 8) idx8[tid] = x[(t0 + tid)*512 + 511];
  __syncthreads();
  for (int i = tid; i < 8*EMB; i += 256){
    int q = i >> 7, r = i & 127;
    embs[q][r] = emb_tab[(long)idx8[q]*EMB + r];
  }
  __syncthreads();
  for (int g = 0; g < 3; g++){
    int j = g*256 + tid;
    float b = bih0[j];
    float acc[8];
    #pragma unroll
    for (int u=0;u<8;u++) acc[u]=b;
    const float4* wrow = (const float4*)(Wih0 + (long)j*EMB);
    #pragma unroll 8
    for (int m=0;m<EMB/4;m++){
      float4 w = wrow[m];
      #pragma unroll
      for (int u=0;u<8;u++){
        acc[u] += w.x*embs[u][4*m+0] + w.y*embs[u][4*m+1]
                + w.z*embs[u][4*m+2] + w.w*embs[u][4*m+3];
      }
    }
    #pragma unroll
    for (int u=0;u<8;u++) xi0[(long)(t0+u)*G3 + j] = acc[u];
  }
  // ---- pack streamed rows: s in [0,128): row = 12*(s/2) + 10 + s%2 ----
  int gid = blockIdx.x*256 + tid;
  for (int e = gid; e < 2*128*256; e += 64*256){
    int L = (e >= 128*256) ? 1 : 0;
    int i = e - L*128*256;
    int s = i >> 8, c = i & 255;
    int row = 12*(s/2) + 10 + (s%2);
    const float* W = L ? Whh1 : Whh0;
    _Float16*    P = L ? wpk1 : wpk0;
    P[i] = (_Float16)W[(long)row*HID + c];
  }
}

// ---------------- pipelined recurrence (1 kernel, 14 blocks) ----------------
// ROUND-20 = ROUND-19 resubmitted verbatim (r19 never ran: container infra
// failure with no timing data; kernel re-audited vs the passing r18 — same
// sync structure, bounds verified, LDS 138.5K <= 160K HW limit).
// r18 post-mortem: grant model confirmed (512thr -> 128 VGPRs) but step
// stayed ~3595 cy. Mis-budget found: 3 stream rows/group = 98 KB/step from
// L2 (not 25 KB) = ~1750 cy @56 B/cy — the dominant feed term (also
// retro-explains r15's 3350: ~200 KB/step spill reload, same path).
// Rebalance feeds: 6 rows regs (96 dw) + 4 rows LDS (131 KB, ~1024 cy
// @128 B/cy) + 2 rows stream (65.5 KB, ~600-1170 cy, partially L1-res).
// All feed terms now <= ~1100 cy, overlapping the 768 cy fdot2 floor.
// Tells: LDS_Block_Size ~139 KB; pipe 779 -> ~500-620 us.
#define SHUF(V,A,B) __builtin_shufflevector(V,V,A,B)
#define WR24(X) X(0,0) X(0,1) X(0,2) X(0,3) X(1,0) X(1,1) X(1,2) X(1,3) \
                X(2,0) X(2,1) X(2,2) X(2,3) X(3,0) X(3,1) X(3,2) X(3,3) \
                X(4,0) X(4,1) X(4,2) X(4,3) X(5,0) X(5,1) X(5,2) X(5,3)

template<int MODE>  // 0 = producer (layer 1), 1 = consumer (layer 2)
__device__ __forceinline__ void rec_layer(const float* __restrict__ Whh,
    const float* __restrict__ bhh, const float* __restrict__ xi,
    const _Float16* __restrict__ wpk,
    _Float16* __restrict__ h16out, float* __restrict__ f32out,
    unsigned* __restrict__ flagB, unsigned* __restrict__ cntB,
    _Float16 (*hbuf)[8*40], half8* ldsw, float* gh, float* bhhL)
{
  int tid = threadIdx.x;
  int g   = tid >> 3;        // 0..63 : rows 12g..12g+11
  int o   = tid & 7;         // col chunk [32o, 32o+32)

#define WDECL(I,C) half8 w##I##_##C;
  WR24(WDECL)
#define WLOAD(I,C) { \
    const float4* p_ = (const float4*)(Whh + (long)(12*g+(I))*HID + 32*o + 8*(C)); \
    float4 u_ = p_[0], v_ = p_[1]; \
    w##I##_##C = (half8){(_Float16)u_.x,(_Float16)u_.y,(_Float16)u_.z,(_Float16)u_.w, \
                         (_Float16)v_.x,(_Float16)v_.y,(_Float16)v_.z,(_Float16)v_.w}; }
  WR24(WLOAD)

  // LDS rows I=6..9 (16 half8/thread), thread-private conflict-free layout
  #pragma unroll
  for (int k = 0; k < 16; k++){
    int row = 12*g + 6 + (k >> 2);
    int C = k & 3;
    const float4* p_ = (const float4*)(Whh + (long)row*HID + 32*o + 8*C);
    float4 u_ = p_[0], v_ = p_[1];
    ldsw[k*THR + tid] = (half8){(_Float16)u_.x,(_Float16)u_.y,(_Float16)u_.z,(_Float16)u_.w,
                                (_Float16)v_.x,(_Float16)v_.y,(_Float16)v_.z,(_Float16)v_.w};
  }
  // streamed rows I=10..11 base pointers (packed f16, row s = 2g+j)
  const half8* sp0 = (const half8*)(wpk + ((long)(2*g+0))*HID + 32*o);
  const half8* sp1 = (const half8*)(wpk + ((long)(2*g+1))*HID + 32*o);

  float hprev = 0.f;
  float xr=0.f, xz=0.f, xn=0.f;
  for (int i = tid; i < G3; i += THR) bhhL[i] = bhh[i];
  if (tid < 80) ((half8*)hbuf)[tid] = (half8)(_Float16)0;  // zero both buffers

  if (MODE == 1 && tid == CTL){   // wait for batch 0 of xi1
    while (__hip_atomic_load(&cntB[0], __ATOMIC_RELAXED, __HIP_MEMORY_SCOPE_AGENT) < NB1)
      __builtin_amdgcn_s_sleep(1);
    __threadfence();
  }
  __syncthreads();
  if (tid < HID){  // xi for t=0 (MODE1: safe after cntB[0] confirmed)
    xr = xi[tid]; xz = xi[HID+tid]; xn = xi[2*HID+tid];
  }

  for (int t = 0; t < TS; t++){
    // consumer: at batch boundaries confirm the NEXT batch so the
    // elementwise-phase prefetch of xi[t+1] is safe.
    if (MODE == 1 && tid == CTL && ((t+1) & (BSZ-1)) == 0 && t+1 < TS){
      unsigned b = (unsigned)(t+1) >> 3;
      while (__hip_atomic_load(&cntB[b], __ATOMIC_RELAXED, __HIP_MEMORY_SCOPE_AGENT) < NB1)
        __builtin_amdgcn_s_sleep(1);
      __threadfence();
    }

    // ---- dot phase: 12 rows/thread from regs + LDS + L2 stream ----
    const half8* hp = (const half8*)(&hbuf[t & 1][o*40]);
    float a0=0.f,a1=0.f,a2=0.f,a3=0.f,a4=0.f,a5=0.f,
          a6=0.f,a7=0.f,a8=0.f,a9=0.f,a10=0.f,a11=0.f;
#define D8(ACC, WV, HV) \
    ACC = __builtin_amdgcn_fdot2(SHUF(WV,0,1), SHUF(HV,0,1), ACC, false); \
    ACC = __builtin_amdgcn_fdot2(SHUF(WV,2,3), SHUF(HV,2,3), ACC, false); \
    ACC = __builtin_amdgcn_fdot2(SHUF(WV,4,5), SHUF(HV,4,5), ACC, false); \
    ACC = __builtin_amdgcn_fdot2(SHUF(WV,6,7), SHUF(HV,6,7), ACC, false);
#define CHUNK(C) { \
    half8 s0 = sp0[C]; half8 s1 = sp1[C]; \
    half8 l0 = ldsw[(0*4+(C))*THR + tid]; \
    half8 l1 = ldsw[(1*4+(C))*THR + tid]; \
    half8 l2 = ldsw[(2*4+(C))*THR + tid]; \
    half8 l3 = ldsw[(3*4+(C))*THR + tid]; \
    half8 hv = hp[C]; \
    D8(a0, w0_##C, hv) D8(a1, w1_##C, hv) D8(a2, w2_##C, hv) \
    D8(a3, w3_##C, hv) D8(a4, w4_##C, hv) D8(a5, w5_##C, hv) \
    D8(a6, l0, hv) D8(a7, l1, hv) D8(a8, l2, hv) D8(a9, l3, hv) \
    D8(a10, s0, hv) D8(a11, s1, hv) }
    CHUNK(0) CHUNK(1) CHUNK(2) CHUNK(3)

    // ---- butterfly: rows 0..7 (8-tree), rows 8..11 (4-tree) ----
    bool b0 = o & 1, b1 = o & 2, b2 = o & 4;
    float s, r_;
    s = b0 ? a0 : a1; r_ = __shfl_xor(s, 1, 64); float c0 = (b0 ? a1 : a0) + r_;
    s = b0 ? a2 : a3; r_ = __shfl_xor(s, 1, 64); float c1 = (b0 ? a3 : a2) + r_;
    s = b0 ? a4 : a5; r_ = __shfl_xor(s, 1, 64); float c2 = (b0 ? a5 : a4) + r_;
    s = b0 ? a6 : a7; r_ = __shfl_xor(s, 1, 64); float c3 = (b0 ? a7 : a6) + r_;
    s = b1 ? c0 : c1; r_ = __shfl_xor(s, 2, 64); float d0 = (b1 ? c1 : c0) + r_;
    s = b1 ? c2 : c3; r_ = __shfl_xor(s, 2, 64); float d1 = (b1 ? c3 : c2) + r_;
    s = b2 ? d0 : d1; r_ = __shfl_xor(s, 4, 64); float e  = (b2 ? d1 : d0) + r_;
    gh[12*g + o] = e;
    s = b0 ? a8 : a9;   r_ = __shfl_xor(s, 1, 64); float c4 = (b0 ? a9  : a8 ) + r_;
    s = b0 ? a10 : a11; r_ = __shfl_xor(s, 1, 64); float c5 = (b0 ? a11 : a10) + r_;
    s = b1 ? c4 : c5;   r_ = __shfl_xor(s, 2, 64); float d2 = (b1 ? c5  : c4 ) + r_;
    float e2 = d2 + __shfl_xor(d2, 4, 64);
    if (o < 4) gh[12*g + 8 + o] = e2;
    __syncthreads();

    // ---- elementwise phase: unit j = tid < 256 ----
    if (tid < HID){
      float r = sigmoidf_(xr + bhhL[tid] + gh[tid]);
      float z = sigmoidf_(xz + bhhL[HID+tid] + gh[HID+tid]);
      float n = tanhf_(xn + r*(gh[2*HID+tid] + bhhL[2*HID+tid]));
      float hnew = (1.0f - z)*n + z*hprev;
      hprev = hnew;
      if (MODE == 1) f32out[(long)t*HID + tid] = hnew;
      float partner = __shfl_xor(hnew, 1, 64);
      if ((tid & 1) == 0){
        f16x2 p; p.x = (_Float16)hnew; p.y = (_Float16)partner;
        *(f16x2*)(&hbuf[(t+1)&1][(tid>>5)*40 + (tid&31)]) = p;
        if (MODE == 0) *(f16x2*)(h16out + (long)t*HID + tid) = p;
      }
      if (t+1 < TS){  // prefetch xi[t+1]; latency rides under next dot phase
        const float* xp = xi + (long)(t+1)*G3;
        xr = xp[tid]; xz = xp[HID+tid]; xn = xp[2*HID+tid];
      }
    }
    __syncthreads();   // drains h stores (vmcnt) before publish
    // producer: publish once per batch
    if (MODE == 0 && tid == CTL && ((t+1) & (BSZ-1)) == 0){
      __threadfence();
      __hip_atomic_store(&flagB[t >> 3], 1u, __ATOMIC_RELEASE, __HIP_MEMORY_SCOPE_AGENT);
    }
  }
}

__device__ __forceinline__ void xi1_stage(const float* __restrict__ Wih1,
    const float* __restrict__ bih1, const _Float16* __restrict__ h16,
    float* __restrict__ xi1, unsigned* __restrict__ flagB,
    unsigned* __restrict__ cntB, int slice)
{
  int tid = threadIdx.x;
  int r = tid >> 3, o = tid & 7;        // row r of slice; cols [32o,32o+32)
  int row = slice*RPB + r;
  half8 w0,w1,w2,w3;                    // 16 VGPRs, register-resident slice
  {
    const float4* wp = (const float4*)(Wih1 + (long)row*HID + o*32);
    float4 p0=wp[0],p1=wp[1],p2=wp[2],p3=wp[3],p4=wp[4],p5=wp[5],p6=wp[6],p7=wp[7];
    w0 = (half8){(_Float16)p0.x,(_Float16)p0.y,(_Float16)p0.z,(_Float16)p0.w,
                 (_Float16)p1.x,(_Float16)p1.y,(_Float16)p1.z,(_Float16)p1.w};
    w1 = (half8){(_Float16)p2.x,(_Float16)p2.y,(_Float16)p2.z,(_Float16)p2.w,
                 (_Float16)p3.x,(_Float16)p3.y,(_Float16)p3.z,(_Float16)p3.w};
    w2 = (half8){(_Float16)p4.x,(_Float16)p4.y,(_Float16)p4.z,(_Float16)p4.w,
                 (_Float16)p5.x,(_Float16)p5.y,(_Float16)p5.z,(_Float16)p5.w};
    w3 = (half8){(_Float16)p6.x,(_Float16)p6.y,(_Float16)p6.z,(_Float16)p6.w,
                 (_Float16)p7.x,(_Float16)p7.y,(_Float16)p7.z,(_Float16)p7.w};
  }
  float bias = bih1[row];

  for (int b = 0; b < TS/BSZ; b++){
    if (tid == 0){
      while (__hip_atomic_load(&flagB[b], __ATOMIC_RELAXED, __HIP_MEMORY_SCOPE_AGENT) == 0u)
        __builtin_amdgcn_s_sleep(1);
      __threadfence();
    }
    __syncthreads();
    #pragma unroll 4
    for (int u = 0; u < BSZ; u++){
      int t = b*BSZ + u;
      const half8* hp = (const half8*)(h16 + (long)t*HID + o*32);
      half8 h0 = hp[0], h1 = hp[1], h2 = hp[2], h3 = hp[3];
      float acc = 0.f;
#define XDOT(W,H) \
      acc = __builtin_amdgcn_fdot2(SHUF(W,0,1), SHUF(H,0,1), acc, false); \
      acc = __builtin_amdgcn_fdot2(SHUF(W,2,3), SHUF(H,2,3), acc, false); \
      acc = __builtin_amdgcn_fdot2(SHUF(W,4,5), SHUF(H,4,5), acc, false); \
      acc = __builtin_amdgcn_fdot2(SHUF(W,6,7), SHUF(H,6,7), acc, false);
      XDOT(w0,h0) XDOT(w1,h1) XDOT(w2,h2) XDOT(w3,h3)
      acc += __shfl_xor(acc, 1, 64);
      acc += __shfl_xor(acc, 2, 64);
      acc += __shfl_xor(acc, 4, 64);
      if (o == 0) xi1[(long)t*G3 + row] = acc + bias;
    }
    __syncthreads();   // drains each thread's stores (vmcnt) before fence
    if (tid == 0){
      __threadfence();
      atomicAdd(&cntB[b], 1u);
    }
  }
}

__global__ __launch_bounds__(THR, 2)
void pipe_kernel(
    const float* __restrict__ Whh0, const float* __restrict__ bhh0,
    const float* __restrict__ xi0,
    const float* __restrict__ Wih1, const float* __restrict__ bih1,
    const float* __restrict__ Whh1, const float* __restrict__ bhh1,
    const _Float16* __restrict__ wpk0, const _Float16* __restrict__ wpk1,
    _Float16* __restrict__ h1f16, float* __restrict__ xi1,
    float* __restrict__ h2, unsigned* __restrict__ flagB,
    unsigned* __restrict__ cntB)
{
  __shared__ __align__(16) half8 ldsw[16*THR];         // 131072 B
  __shared__ __align__(16) _Float16 hbuf[2][8*40];     // 1280 B
  __shared__ float gh[G3];                             // 3072 B
  __shared__ float bhhL[G3];                           // 3072 B
  int bid = blockIdx.x;
  if (bid == 0)
    rec_layer<0>(Whh0, bhh0, xi0, wpk0, h1f16, nullptr, flagB, cntB, hbuf, ldsw, gh, bhhL);
  else if (bid == 13)
    rec_layer<1>(Whh1, bhh1, xi1, wpk1, nullptr, h2, flagB, cntB, hbuf, ldsw, gh, bhhL);
  else
    xi1_stage(Wih1, bih1, h1f16, xi1, flagB, cntB, bid - 1);
}

// K5: logits[t][c] = b_out[c] + sum_i h2[t][i] * W_out[c][i]
__global__ __launch_bounds__(1024) void logits_kernel(const float* __restrict__ h2,
    const float* __restrict__ Wout, const float* __restrict__ bout,
    float* __restrict__ out)
{
  __shared__ __align__(16) float wsm[2*HID];
  __shared__ float bs[2];
  int tid = threadIdx.x;
  if (tid < 2*HID) wsm[tid] = Wout[tid];
  if (tid < 2)     bs[tid]  = bout[tid];
  __syncthreads();
  int t = tid >> 1, c = tid & 1;
  const float4* hr = (const float4*)(h2 + (long)t*HID);
  const float4* wr = (const float4*)(wsm + c*HID);
  float acc = bs[c];
  #pragma unroll 8
  for (int m=0;m<HID/4;m++){
    float4 h = hr[m]; float4 wv = wr[m];
    acc += h.x*wv.x + h.y*wv.y + h.z*wv.z + h.w*wv.w;
  }
  out[tid] = acc;
}

extern "C" void kernel_launch(void* const* d_in, const int* in_sizes, int n_in,
                              void* d_out, int out_size, void* d_ws, size_t ws_size,
                              hipStream_t stream)
{
  const int*   x    = (const int*)  d_in[0];
  const float* emb  = (const float*)d_in[1];
  const float* Wih0 = (const float*)d_in[2];
  const float* Whh0 = (const float*)d_in[3];
  const float* bih0 = (const float*)d_in[4];
  const float* bhh0 = (const float*)d_in[5];
  const float* Wih1 = (const float*)d_in[6];
  const float* Whh1 = (const float*)d_in[7];
  const float* bih1 = (const float*)d_in[8];
  const float* bhh1 = (const float*)d_in[9];
  const float* Wout = (const float*)d_in[10];
  const float* bout = (const float*)d_in[11];
  float* out = (float*)d_out;

  char* ws = (char*)d_ws;
  float*     xi0   = (float*)(ws);                       // 512*768 f32 = 1.5 MB
  float*     xi1   = (float*)(ws + 1572864);             // 512*768 f32 = 1.5 MB
  _Float16*  h1f16 = (_Float16*)(ws + 3145728);          // 512*256 f16 = 256 KB
  float*     h2    = (float*)(ws + 3407872);             // 512*256 f32 = 512 KB
  unsigned*  flagB = (unsigned*)(ws + 3932160);          // 64 u32
  unsigned*  cntB  = (unsigned*)(ws + 3934208);          // 64 u32
  _Float16*  wpk0  = (_Float16*)(ws + 3936256);          // 128*256 f16 = 64 KB
  _Float16*  wpk1  = (_Float16*)(ws + 4001792);          // 128*256 f16 = 64 KB

  hipMemsetAsync(ws + 3932160, 0, 4096, stream);
  xi0_kernel<<<64, 256, 0, stream>>>(x, emb, Wih0, bih0, xi0,
                                     Whh0, Whh1, wpk0, wpk1);
  pipe_kernel<<<14, THR, 0, stream>>>(Whh0, bhh0, xi0, Wih1, bih1,
                                      Whh1, bhh1, wpk0, wpk1,
                                      h1f16, xi1, h2, flagB, cntB);
  logits_kernel<<<1, 1024, 0, stream>>>(h2, Wout, bout, out);
}

// Round 8
// 889.619 us; speedup vs baseline: 1.0093x; 1.0093x over previous
//
#include <hip/hip_runtime.h>
#include <hip/hip_fp16.h>

typedef _Float16 f16x2 __attribute__((ext_vector_type(2)));
typedef _Float16 half8 __attribute__((ext_vector_type(8)));

#define TS  512
#define HID 256
#define G3  768
#define EMB 128
#define THR 512   // threads per pipe block
#define NB1 12    // xi1 producer blocks
#define RPB 64    // rows per xi1-stage block
#define CTL 511   // poller/publisher thread
#define BSZ 8     // handshake batch (steps)

__device__ __forceinline__ float sigmoidf_(float x){ return 1.0f/(1.0f+__expf(-x)); }
__device__ __forceinline__ float tanhf_(float x){
  float e = __expf(-2.0f*fabsf(x));
  float t = (1.0f-e)/(1.0f+e);
  return copysignf(t,x);
}

// K1: xi0[t][j] = bih0[j] + sum_k Wih0[j][k] * emb[x[t,511]][k]
__global__ __launch_bounds__(256) void xi0_kernel(const int* __restrict__ x,
    const float* __restrict__ emb_tab, const float* __restrict__ Wih0,
    const float* __restrict__ bih0, float* __restrict__ xi0)
{
  __shared__ float embs[8][EMB];
  __shared__ int idx8[8];
  int tid = threadIdx.x;
  int t0  = blockIdx.x * 8;
  if (tid < 8) idx8[tid] = x[(t0 + tid)*512 + 511];
  __syncthreads();
  for (int i = tid; i < 8*EMB; i += 256){
    int q = i >> 7, r = i & 127;
    embs[q][r] = emb_tab[(long)idx8[q]*EMB + r];
  }
  __syncthreads();
  for (int g = 0; g < 3; g++){
    int j = g*256 + tid;
    float b = bih0[j];
    float acc[8];
    #pragma unroll
    for (int u=0;u<8;u++) acc[u]=b;
    const float4* wrow = (const float4*)(Wih0 + (long)j*EMB);
    #pragma unroll 8
    for (int m=0;m<EMB/4;m++){
      float4 w = wrow[m];
      #pragma unroll
      for (int u=0;u<8;u++){
        acc[u] += w.x*embs[u][4*m+0] + w.y*embs[u][4*m+1]
                + w.z*embs[u][4*m+2] + w.w*embs[u][4*m+3];
      }
    }
    #pragma unroll
    for (int u=0;u<8;u++) xi0[(long)(t0+u)*G3 + j] = acc[u];
  }
}

// ---------------- pipelined recurrence (1 kernel, 14 blocks) ----------------
// ROUND-21: sum-of-ports model now fits r15/r18/r20 within 5%: off-register
// weight bytes (~190 KB/step) stream through DS(85 B/cy)+VMEM(56 B/cy) with
// NO overlap (zero reg headroom to pipeline chunks). Allocator grants each
// wg exactly HALF the CU RF (2-wg assumption, LDS-blind; 84@768t, 128@512t)
// — 5 rounds of evidence. This round: last untried direct-allocation
// attribute, amdgpu_num_vgpr(256) (+waves_per_eu(2,2)), with the row split
// configured so failure is a wash: 10 reg rows (160 dw) + 2 LDS rows + 0
// stream. Honored (VGPR>=~200): zero spill, off-reg 97 KB -> step ~1500-
// 1800 cy -> pipe ~340-420 us. Ignored (VGPR=128): ~62 dw spill = 127 KB
// scratch replaces the old stream at the same port -> wash (~760-800 us).
#define SHUF(V,A,B) __builtin_shufflevector(V,V,A,B)
#define WR40(X) X(0,0) X(0,1) X(0,2) X(0,3) X(1,0) X(1,1) X(1,2) X(1,3) \
                X(2,0) X(2,1) X(2,2) X(2,3) X(3,0) X(3,1) X(3,2) X(3,3) \
                X(4,0) X(4,1) X(4,2) X(4,3) X(5,0) X(5,1) X(5,2) X(5,3) \
                X(6,0) X(6,1) X(6,2) X(6,3) X(7,0) X(7,1) X(7,2) X(7,3) \
                X(8,0) X(8,1) X(8,2) X(8,3) X(9,0) X(9,1) X(9,2) X(9,3)

template<int MODE>  // 0 = producer (layer 1), 1 = consumer (layer 2)
__device__ __forceinline__ void rec_layer(const float* __restrict__ Whh,
    const float* __restrict__ bhh, const float* __restrict__ xi,
    _Float16* __restrict__ h16out, float* __restrict__ f32out,
    unsigned* __restrict__ flagB, unsigned* __restrict__ cntB,
    _Float16 (*hbuf)[8*40], half8* ldsw, float* gh, float* bhhL)
{
  int tid = threadIdx.x;
  int g   = tid >> 3;        // 0..63 : rows 12g..12g+11
  int o   = tid & 7;         // col chunk [32o, 32o+32)

#define WDECL(I,C) half8 w##I##_##C;
  WR40(WDECL)
#define WLOAD(I,C) { \
    const float4* p_ = (const float4*)(Whh + (long)(12*g+(I))*HID + 32*o + 8*(C)); \
    float4 u_ = p_[0], v_ = p_[1]; \
    w##I##_##C = (half8){(_Float16)u_.x,(_Float16)u_.y,(_Float16)u_.z,(_Float16)u_.w, \
                         (_Float16)v_.x,(_Float16)v_.y,(_Float16)v_.z,(_Float16)v_.w}; }
  WR40(WLOAD)

  // LDS rows I=10..11 (8 half8/thread), thread-private conflict-free layout
  #pragma unroll
  for (int k = 0; k < 8; k++){
    int row = 12*g + 10 + (k >> 2);
    int C = k & 3;
    const float4* p_ = (const float4*)(Whh + (long)row*HID + 32*o + 8*C);
    float4 u_ = p_[0], v_ = p_[1];
    ldsw[k*THR + tid] = (half8){(_Float16)u_.x,(_Float16)u_.y,(_Float16)u_.z,(_Float16)u_.w,
                                (_Float16)v_.x,(_Float16)v_.y,(_Float16)v_.z,(_Float16)v_.w};
  }

  float hprev = 0.f;
  float xr=0.f, xz=0.f, xn=0.f;
  for (int i = tid; i < G3; i += THR) bhhL[i] = bhh[i];
  if (tid < 80) ((half8*)hbuf)[tid] = (half8)(_Float16)0;  // zero both buffers

  if (MODE == 1 && tid == CTL){   // wait for batch 0 of xi1
    while (__hip_atomic_load(&cntB[0], __ATOMIC_RELAXED, __HIP_MEMORY_SCOPE_AGENT) < NB1)
      __builtin_amdgcn_s_sleep(1);
    __threadfence();
  }
  __syncthreads();
  if (tid < HID){  // xi for t=0 (MODE1: safe after cntB[0] confirmed)
    xr = xi[tid]; xz = xi[HID+tid]; xn = xi[2*HID+tid];
  }

  for (int t = 0; t < TS; t++){
    // consumer: at batch boundaries confirm the NEXT batch so the
    // elementwise-phase prefetch of xi[t+1] is safe.
    if (MODE == 1 && tid == CTL && ((t+1) & (BSZ-1)) == 0 && t+1 < TS){
      unsigned b = (unsigned)(t+1) >> 3;
      while (__hip_atomic_load(&cntB[b], __ATOMIC_RELAXED, __HIP_MEMORY_SCOPE_AGENT) < NB1)
        __builtin_amdgcn_s_sleep(1);
      __threadfence();
    }

    // ---- dot phase: 12 rows/thread, 10 from regs + 2 from LDS ----
    const half8* hp = (const half8*)(&hbuf[t & 1][o*40]);
    float a0=0.f,a1=0.f,a2=0.f,a3=0.f,a4=0.f,a5=0.f,
          a6=0.f,a7=0.f,a8=0.f,a9=0.f,a10=0.f,a11=0.f;
#define D8(ACC, WV, HV) \
    ACC = __builtin_amdgcn_fdot2(SHUF(WV,0,1), SHUF(HV,0,1), ACC, false); \
    ACC = __builtin_amdgcn_fdot2(SHUF(WV,2,3), SHUF(HV,2,3), ACC, false); \
    ACC = __builtin_amdgcn_fdot2(SHUF(WV,4,5), SHUF(HV,4,5), ACC, false); \
    ACC = __builtin_amdgcn_fdot2(SHUF(WV,6,7), SHUF(HV,6,7), ACC, false);
#define CHUNK(C) { \
    half8 l0 = ldsw[(0*4+(C))*THR + tid]; \
    half8 l1 = ldsw[(1*4+(C))*THR + tid]; \
    half8 hv = hp[C]; \
    D8(a0, w0_##C, hv) D8(a1, w1_##C, hv) D8(a2, w2_##C, hv) \
    D8(a3, w3_##C, hv) D8(a4, w4_##C, hv) D8(a5, w5_##C, hv) \
    D8(a6, w6_##C, hv) D8(a7, w7_##C, hv) D8(a8, w8_##C, hv) \
    D8(a9, w9_##C, hv) \
    D8(a10, l0, hv) D8(a11, l1, hv) }
    CHUNK(0) CHUNK(1) CHUNK(2) CHUNK(3)

    // ---- butterfly: rows 0..7 (8-tree), rows 8..11 (4-tree) ----
    bool b0 = o & 1, b1 = o & 2, b2 = o & 4;
    float s, r_;
    s = b0 ? a0 : a1; r_ = __shfl_xor(s, 1, 64); float c0 = (b0 ? a1 : a0) + r_;
    s = b0 ? a2 : a3; r_ = __shfl_xor(s, 1, 64); float c1 = (b0 ? a3 : a2) + r_;
    s = b0 ? a4 : a5; r_ = __shfl_xor(s, 1, 64); float c2 = (b0 ? a5 : a4) + r_;
    s = b0 ? a6 : a7; r_ = __shfl_xor(s, 1, 64); float c3 = (b0 ? a7 : a6) + r_;
    s = b1 ? c0 : c1; r_ = __shfl_xor(s, 2, 64); float d0 = (b1 ? c1 : c0) + r_;
    s = b1 ? c2 : c3; r_ = __shfl_xor(s, 2, 64); float d1 = (b1 ? c3 : c2) + r_;
    s = b2 ? d0 : d1; r_ = __shfl_xor(s, 4, 64); float e  = (b2 ? d1 : d0) + r_;
    gh[12*g + o] = e;
    s = b0 ? a8 : a9;   r_ = __shfl_xor(s, 1, 64); float c4 = (b0 ? a9  : a8 ) + r_;
    s = b0 ? a10 : a11; r_ = __shfl_xor(s, 1, 64); float c5 = (b0 ? a11 : a10) + r_;
    s = b1 ? c4 : c5;   r_ = __shfl_xor(s, 2, 64); float d2 = (b1 ? c5  : c4 ) + r_;
    float e2 = d2 + __shfl_xor(d2, 4, 64);
    if (o < 4) gh[12*g + 8 + o] = e2;
    __syncthreads();

    // ---- elementwise phase: unit j = tid < 256 ----
    if (tid < HID){
      float r = sigmoidf_(xr + bhhL[tid] + gh[tid]);
      float z = sigmoidf_(xz + bhhL[HID+tid] + gh[HID+tid]);
      float n = tanhf_(xn + r*(gh[2*HID+tid] + bhhL[2*HID+tid]));
      float hnew = (1.0f - z)*n + z*hprev;
      hprev = hnew;
      if (MODE == 1) f32out[(long)t*HID + tid] = hnew;
      float partner = __shfl_xor(hnew, 1, 64);
      if ((tid & 1) == 0){
        f16x2 p; p.x = (_Float16)hnew; p.y = (_Float16)partner;
        *(f16x2*)(&hbuf[(t+1)&1][(tid>>5)*40 + (tid&31)]) = p;
        if (MODE == 0) *(f16x2*)(h16out + (long)t*HID + tid) = p;
      }
      if (t+1 < TS){  // prefetch xi[t+1]; latency rides under next dot phase
        const float* xp = xi + (long)(t+1)*G3;
        xr = xp[tid]; xz = xp[HID+tid]; xn = xp[2*HID+tid];
      }
    }
    __syncthreads();   // drains h stores (vmcnt) before publish
    // producer: publish once per batch
    if (MODE == 0 && tid == CTL && ((t+1) & (BSZ-1)) == 0){
      __threadfence();
      __hip_atomic_store(&flagB[t >> 3], 1u, __ATOMIC_RELEASE, __HIP_MEMORY_SCOPE_AGENT);
    }
  }
}

__device__ __forceinline__ void xi1_stage(const float* __restrict__ Wih1,
    const float* __restrict__ bih1, const _Float16* __restrict__ h16,
    float* __restrict__ xi1, unsigned* __restrict__ flagB,
    unsigned* __restrict__ cntB, int slice)
{
  int tid = threadIdx.x;
  int r = tid >> 3, o = tid & 7;        // row r of slice; cols [32o,32o+32)
  int row = slice*RPB + r;
  half8 w0,w1,w2,w3;                    // 16 VGPRs, register-resident slice
  {
    const float4* wp = (const float4*)(Wih1 + (long)row*HID + o*32);
    float4 p0=wp[0],p1=wp[1],p2=wp[2],p3=wp[3],p4=wp[4],p5=wp[5],p6=wp[6],p7=wp[7];
    w0 = (half8){(_Float16)p0.x,(_Float16)p0.y,(_Float16)p0.z,(_Float16)p0.w,
                 (_Float16)p1.x,(_Float16)p1.y,(_Float16)p1.z,(_Float16)p1.w};
    w1 = (half8){(_Float16)p2.x,(_Float16)p2.y,(_Float16)p2.z,(_Float16)p2.w,
                 (_Float16)p3.x,(_Float16)p3.y,(_Float16)p3.z,(_Float16)p3.w};
    w2 = (half8){(_Float16)p4.x,(_Float16)p4.y,(_Float16)p4.z,(_Float16)p4.w,
                 (_Float16)p5.x,(_Float16)p5.y,(_Float16)p5.z,(_Float16)p5.w};
    w3 = (half8){(_Float16)p6.x,(_Float16)p6.y,(_Float16)p6.z,(_Float16)p6.w,
                 (_Float16)p7.x,(_Float16)p7.y,(_Float16)p7.z,(_Float16)p7.w};
  }
  float bias = bih1[row];

  for (int b = 0; b < TS/BSZ; b++){
    if (tid == 0){
      while (__hip_atomic_load(&flagB[b], __ATOMIC_RELAXED, __HIP_MEMORY_SCOPE_AGENT) == 0u)
        __builtin_amdgcn_s_sleep(1);
      __threadfence();
    }
    __syncthreads();
    #pragma unroll 4
    for (int u = 0; u < BSZ; u++){
      int t = b*BSZ + u;
      const half8* hp = (const half8*)(h16 + (long)t*HID + o*32);
      half8 h0 = hp[0], h1 = hp[1], h2 = hp[2], h3 = hp[3];
      float acc = 0.f;
#define XDOT(W,H) \
      acc = __builtin_amdgcn_fdot2(SHUF(W,0,1), SHUF(H,0,1), acc, false); \
      acc = __builtin_amdgcn_fdot2(SHUF(W,2,3), SHUF(H,2,3), acc, false); \
      acc = __builtin_amdgcn_fdot2(SHUF(W,4,5), SHUF(H,4,5), acc, false); \
      acc = __builtin_amdgcn_fdot2(SHUF(W,6,7), SHUF(H,6,7), acc, false);
      XDOT(w0,h0) XDOT(w1,h1) XDOT(w2,h2) XDOT(w3,h3)
      acc += __shfl_xor(acc, 1, 64);
      acc += __shfl_xor(acc, 2, 64);
      acc += __shfl_xor(acc, 4, 64);
      if (o == 0) xi1[(long)t*G3 + row] = acc + bias;
    }
    __syncthreads();   // drains each thread's stores (vmcnt) before fence
    if (tid == 0){
      __threadfence();
      atomicAdd(&cntB[b], 1u);
    }
  }
}

__global__
__attribute__((amdgpu_flat_work_group_size(THR, THR),
               amdgpu_waves_per_eu(2, 2),
               amdgpu_num_vgpr(256)))
void pipe_kernel(
    const float* __restrict__ Whh0, const float* __restrict__ bhh0,
    const float* __restrict__ xi0,
    const float* __restrict__ Wih1, const float* __restrict__ bih1,
    const float* __restrict__ Whh1, const float* __restrict__ bhh1,
    _Float16* __restrict__ h1f16, float* __restrict__ xi1,
    float* __restrict__ h2, unsigned* __restrict__ flagB,
    unsigned* __restrict__ cntB)
{
  __shared__ __align__(16) half8 ldsw[8*THR];          // 65536 B
  __shared__ __align__(16) _Float16 hbuf[2][8*40];     // 1280 B
  __shared__ float gh[G3];                             // 3072 B
  __shared__ float bhhL[G3];                           // 3072 B
  int bid = blockIdx.x;
  if (bid == 0)
    rec_layer<0>(Whh0, bhh0, xi0, h1f16, nullptr, flagB, cntB, hbuf, ldsw, gh, bhhL);
  else if (bid == 13)
    rec_layer<1>(Whh1, bhh1, xi1, nullptr, h2, flagB, cntB, hbuf, ldsw, gh, bhhL);
  else
    xi1_stage(Wih1, bih1, h1f16, xi1, flagB, cntB, bid - 1);
}

// K5: logits[t][c] = b_out[c] + sum_i h2[t][i] * W_out[c][i]
__global__ __launch_bounds__(1024) void logits_kernel(const float* __restrict__ h2,
    const float* __restrict__ Wout, const float* __restrict__ bout,
    float* __restrict__ out)
{
  __shared__ __align__(16) float wsm[2*HID];
  __shared__ float bs[2];
  int tid = threadIdx.x;
  if (tid < 2*HID) wsm[tid] = Wout[tid];
  if (tid < 2)     bs[tid]  = bout[tid];
  __syncthreads();
  int t = tid >> 1, c = tid & 1;
  const float4* hr = (const float4*)(h2 + (long)t*HID);
  const float4* wr = (const float4*)(wsm + c*HID);
  float acc = bs[c];
  #pragma unroll 8
  for (int m=0;m<HID/4;m++){
    float4 h = hr[m]; float4 wv = wr[m];
    acc += h.x*wv.x + h.y*wv.y + h.z*wv.z + h.w*wv.w;
  }
  out[tid] = acc;
}

extern "C" void kernel_launch(void* const* d_in, const int* in_sizes, int n_in,
                              void* d_out, int out_size, void* d_ws, size_t ws_size,
                              hipStream_t stream)
{
  const int*   x    = (const int*)  d_in[0];
  const float* emb  = (const float*)d_in[1];
  const float* Wih0 = (const float*)d_in[2];
  const float* Whh0 = (const float*)d_in[3];
  const float* bih0 = (const float*)d_in[4];
  const float* bhh0 = (const float*)d_in[5];
  const float* Wih1 = (const float*)d_in[6];
  const float* Whh1 = (const float*)d_in[7];
  const float* bih1 = (const float*)d_in[8];
  const float* bhh1 = (const float*)d_in[9];
  const float* Wout = (const float*)d_in[10];
  const float* bout = (const float*)d_in[11];
  float* out = (float*)d_out;

  char* ws = (char*)d_ws;
  float*     xi0   = (float*)(ws);                       // 512*768 f32 = 1.5 MB
  float*     xi1   = (float*)(ws + 1572864);             // 512*768 f32 = 1.5 MB
  _Float16*  h1f16 = (_Float16*)(ws + 3145728);          // 512*256 f16 = 256 KB
  float*     h2    = (float*)(ws + 3407872);             // 512*256 f32 = 512 KB
  unsigned*  flagB = (unsigned*)(ws + 3932160);          // 64 u32
  unsigned*  cntB  = (unsigned*)(ws + 3934208);          // 64 u32

  hipMemsetAsync(ws + 3932160, 0, 4096, stream);
  xi0_kernel<<<64, 256, 0, stream>>>(x, emb, Wih0, bih0, xi0);
  pipe_kernel<<<14, THR, 0, stream>>>(Whh0, bhh0, xi0, Wih1, bih1,
                                      Whh1, bhh1, h1f16, xi1, h2, flagB, cntB);
  logits_kernel<<<1, 1024, 0, stream>>>(h2, Wout, bout, out);
}